// Round 1
// baseline (338.289 us; speedup 1.0000x reference)
//
#include <hip/hip_runtime.h>

// MomentumLora: out[M,2304] = x[M,768] @ (concat(Aq@Bq, Ak@Bk, Av@Bv)[768,2304] * 1/16)
// Factored as: y[M,48] = (x @ [Aq|Ak|Av]) * s   (stage 1, split-K=2 into d_ws)
//              out[:, z*768:(z+1)*768] = y[:, z*16:(z+1)*16] @ B_z   (stage 2)
// M = 128*197 = 25216 (divisible by 64), dim=768, r=16, scaling=1/16.

#define DIM   768
#define RNK   16
#define NCOLS 48          // 3*r
#define XS_STRIDE 52      // 48 + 4 pad: float4-aligned, conflict-free scalar reads

// ---------------- Stage 1: y_partial[split][M][48] ----------------
// 192 threads (3 waves), tile 64 rows x 48 cols, K chunked by 48.
__global__ __launch_bounds__(192) void lora_stage1(
    const float* __restrict__ x,
    const float* __restrict__ Aq, const float* __restrict__ Ak,
    const float* __restrict__ Av,
    const int* __restrict__ depth_id,
    float* __restrict__ ypart, int kspan, int M)
{
    __shared__ float xs[64 * XS_STRIDE];
    __shared__ float as[48 * NCOLS];

    const int t     = threadIdx.x;
    const int row0  = blockIdx.x * 64;
    const int kbase = blockIdx.y * kspan;

    const int dep = depth_id[0];
    const size_t aoff = (size_t)dep * DIM * RNK;
    const float* Ap0 = Aq + aoff;
    const float* Ap1 = Ak + aoff;
    const float* Ap2 = Av + aoff;

    const int cg = t % 12;   // col group of 4 (cols 4*cg .. 4*cg+3)
    const int rs = t / 12;   // 0..15 row slot; rows rs+16*i

    // Precompute per-j staging coordinates (fixed across chunks).
    int xr[4], xk4[4];
    #pragma unroll
    for (int j = 0; j < 4; j++) { int f = t + j * 192; xr[j] = f / 12; xk4[j] = f % 12; }
    int ak_[3], ac4[3];
    const float* abase[3];
    #pragma unroll
    for (int j = 0; j < 3; j++) {
        int f = t + j * 192;
        ak_[j] = f / 12; ac4[j] = f % 12;
        int z = ac4[j] >> 2, cq = ac4[j] & 3;
        const float* Ap = (z == 0) ? Ap0 : ((z == 1) ? Ap1 : Ap2);
        abase[j] = Ap + 4 * cq;
    }

    float acc[4][4];
    #pragma unroll
    for (int i = 0; i < 4; i++)
        #pragma unroll
        for (int c = 0; c < 4; c++) acc[i][c] = 0.f;

    for (int kc = 0; kc < kspan; kc += 48) {
        const int k0 = kbase + kc;
        // stage x tile: 64 rows x 48 k, float4 loads (coalesced 192B row segments)
        #pragma unroll
        for (int j = 0; j < 4; j++) {
            const float4 v = *reinterpret_cast<const float4*>(
                &x[(size_t)(row0 + xr[j]) * DIM + k0 + 4 * xk4[j]]);
            *reinterpret_cast<float4*>(&xs[xr[j] * XS_STRIDE + 4 * xk4[j]]) = v;
        }
        // stage A tile: 48 k x 48 cols (z-major col order)
        #pragma unroll
        for (int j = 0; j < 3; j++) {
            const float4 v = *reinterpret_cast<const float4*>(
                &abase[j][(size_t)(k0 + ak_[j]) * RNK]);
            *reinterpret_cast<float4*>(&as[ak_[j] * NCOLS + 4 * ac4[j]]) = v;
        }
        __syncthreads();
        #pragma unroll 8
        for (int k = 0; k < 48; k++) {
            const float4 av = *reinterpret_cast<const float4*>(&as[k * NCOLS + 4 * cg]);
            #pragma unroll
            for (int i = 0; i < 4; i++) {
                const float xv = xs[(rs + 16 * i) * XS_STRIDE + k];
                acc[i][0] = fmaf(xv, av.x, acc[i][0]);
                acc[i][1] = fmaf(xv, av.y, acc[i][1]);
                acc[i][2] = fmaf(xv, av.z, acc[i][2]);
                acc[i][3] = fmaf(xv, av.w, acc[i][3]);
            }
        }
        __syncthreads();
    }

    const float s = 0.0625f;  // LORA_ALPHA / RANK
    #pragma unroll
    for (int i = 0; i < 4; i++) {
        float4 v;
        v.x = acc[i][0] * s; v.y = acc[i][1] * s;
        v.z = acc[i][2] * s; v.w = acc[i][3] * s;
        *reinterpret_cast<float4*>(
            &ypart[((size_t)blockIdx.y * M + row0 + rs + 16 * i) * NCOLS + 4 * cg]) = v;
    }
}

// ---------------- Stage 2: out tile 64 rows x 256 cols, K=16 ----------------
__global__ __launch_bounds__(256) void lora_stage2(
    const float* __restrict__ yp,
    const float* __restrict__ Bq, const float* __restrict__ Bk,
    const float* __restrict__ Bv,
    const int* __restrict__ depth_id,
    float* __restrict__ out, int nsplit, int M)
{
    __shared__ float Bs[16 * 256];
    __shared__ float Ys[64 * 16];

    const int t    = threadIdx.x;
    const int row0 = blockIdx.x * 64;
    const int col0 = blockIdx.y * 256;     // 0..2303 in steps of 256
    const int z    = col0 / DIM;           // which of q/k/v
    const int c0z  = col0 - z * DIM;       // col offset inside B_z

    const int dep = depth_id[0];
    const float* Bz = ((z == 0) ? Bq : ((z == 1) ? Bk : Bv)) + (size_t)dep * RNK * DIM;

    // stage B panel: 16 x 256 floats, float4 coalesced
    #pragma unroll
    for (int j = 0; j < 4; j++) {
        int f = t + j * 256;
        int k = f >> 6, c = f & 63;
        *reinterpret_cast<float4*>(&Bs[k * 256 + 4 * c]) =
            *reinterpret_cast<const float4*>(&Bz[(size_t)k * DIM + c0z + 4 * c]);
    }
    // stage y tile: 64 rows x 16 (sum split-K partials)
    {
        int r = t >> 2, q = t & 3;
        size_t base = (size_t)(row0 + r) * NCOLS + z * RNK + 4 * q;
        float4 a = *reinterpret_cast<const float4*>(&yp[base]);
        if (nsplit == 2) {
            const float4 b = *reinterpret_cast<const float4*>(&yp[(size_t)M * NCOLS + base]);
            a.x += b.x; a.y += b.y; a.z += b.z; a.w += b.w;
        }
        *reinterpret_cast<float4*>(&Ys[r * 16 + 4 * q]) = a;
    }
    __syncthreads();

    const int c4 = t & 63;   // float4 column 0..63
    const int rs = t >> 6;   // 0..3; rows rs + 4*i

    float4 bk[16];
    #pragma unroll
    for (int k = 0; k < 16; k++)
        bk[k] = *reinterpret_cast<const float4*>(&Bs[k * 256 + 4 * c4]);

    #pragma unroll
    for (int i = 0; i < 16; i++) {
        const int r = rs + 4 * i;
        const float* yr = &Ys[r * 16];
        float4 acc; acc.x = acc.y = acc.z = acc.w = 0.f;
        #pragma unroll
        for (int k = 0; k < 16; k++) {
            const float yv = yr[k];
            acc.x = fmaf(yv, bk[k].x, acc.x);
            acc.y = fmaf(yv, bk[k].y, acc.y);
            acc.z = fmaf(yv, bk[k].z, acc.z);
            acc.w = fmaf(yv, bk[k].w, acc.w);
        }
        *reinterpret_cast<float4*>(&out[(size_t)(row0 + r) * (3 * DIM) + col0 + 4 * c4]) = acc;
    }
}

extern "C" void kernel_launch(void* const* d_in, const int* in_sizes, int n_in,
                              void* d_out, int out_size, void* d_ws, size_t ws_size,
                              hipStream_t stream) {
    const float* x  = (const float*)d_in[0];
    const float* Aq = (const float*)d_in[1];
    const float* Bq = (const float*)d_in[2];
    const float* Ak = (const float*)d_in[3];
    const float* Bk = (const float*)d_in[4];
    const float* Av = (const float*)d_in[5];
    const float* Bv = (const float*)d_in[6];
    const int* dep  = (const int*)d_in[7];
    float* out = (float*)d_out;
    float* y   = (float*)d_ws;

    const int M = in_sizes[0] / DIM;  // 25216
    const size_t y_bytes_one = (size_t)M * NCOLS * sizeof(float);
    const int nsplit = (ws_size >= 2 * y_bytes_one) ? 2 : 1;
    const int kspan = DIM / nsplit;

    lora_stage1<<<dim3(M / 64, nsplit), 192, 0, stream>>>(x, Aq, Ak, Av, dep, y, kspan, M);
    lora_stage2<<<dim3(M / 64, (3 * DIM) / 256), 256, 0, stream>>>(y, Bq, Bk, Bv, dep, out, nsplit, M);
}

// Round 2
// 333.789 us; speedup vs baseline: 1.0135x; 1.0135x over previous
//
#include <hip/hip_runtime.h>

// MomentumLora: out[M,2304] = x[M,768] @ (concat(Aq@Bq, Ak@Bk, Av@Bv) * 1/16)
// Factored:  y[M,48] = (x @ [Aq|Ak|Av]) * s     (stage 1, split-K into d_ws)
//            out[:, z*768:(z+1)*768] = y[:, z*16:(z+1)*16] @ B_z   (stage 2)
// M = 128*197 = 25216, dim = 768, r = 16, s = 1/16.

#define DIM   768
#define RNK   16
#define NCOLS 48
#define XS_STRIDE 52   // 48 + 4 pad (208B, 16B-aligned rows, bank-spread)

typedef float f32x4 __attribute__((ext_vector_type(4)));

// ---------------- Stage 1: ypart[split][M][48] = x-slice @ Acat * ... ----------------
// 192 threads (3 waves). Tile: 128 rows x 48 cols, K chunks of 48.
// Thread = (rg 0..15, cg 0..11): owns rows rg+16i (i<8), cols 4cg..4cg+3.
// Per 4-k group: 8 xs b128 + 4 as b128 -> 128 FMA (LDS ~1.5B/FMA, VALU-bound).
__global__ __launch_bounds__(192) void lora_stage1(
    const float* __restrict__ x,
    const float* __restrict__ Aq, const float* __restrict__ Ak,
    const float* __restrict__ Av,
    const int* __restrict__ depth_id,
    float* __restrict__ ypart, int kspan, int M)
{
    __shared__ float xs[128 * XS_STRIDE];   // 26.6 KB
    __shared__ float as[48 * NCOLS];        //  9.2 KB

    const int t  = threadIdx.x;
    const int rg = t / 12;
    const int cg = t % 12;
    const int row0  = blockIdx.x * 128;
    const int kbase = blockIdx.y * kspan;

    const int dep = depth_id[0];
    const size_t aoff = (size_t)dep * DIM * RNK;
    const float* Ab0 = Aq + aoff;
    const float* Ab1 = Ak + aoff;
    const float* Ab2 = Av + aoff;

    f32x4 acc[8] = {};   // acc[i] = 4 cols for row rg+16i

    for (int kc = 0; kc < kspan; kc += 48) {
        const int k0 = kbase + kc;
        // stage x tile: 128 rows x 48 k  (1536 float4s, nontemporal)
        #pragma unroll
        for (int j = 0; j < 8; j++) {
            const int f = t + j * 192;
            const int r = f / 12, k4 = f % 12;
            const f32x4 v = __builtin_nontemporal_load(
                reinterpret_cast<const f32x4*>(&x[(size_t)(row0 + r) * DIM + k0 + 4 * k4]));
            *reinterpret_cast<f32x4*>(&xs[r * XS_STRIDE + 4 * k4]) = v;
        }
        // stage A tile: 48 k x 48 cols (q|k|v col-major groups)
        #pragma unroll
        for (int j = 0; j < 3; j++) {
            const int f = t + j * 192;
            const int k = f / 12, c4 = f % 12;
            const int z = c4 >> 2, cq = c4 & 3;
            const float* Ap = (z == 0) ? Ab0 : ((z == 1) ? Ab1 : Ab2);
            const f32x4 v = *reinterpret_cast<const f32x4*>(&Ap[(size_t)(k0 + k) * RNK + 4 * cq]);
            *reinterpret_cast<f32x4*>(&as[k * NCOLS + 4 * c4]) = v;
        }
        __syncthreads();

        #pragma unroll 2
        for (int kk = 0; kk < 48; kk += 4) {
            f32x4 xf[8], af[4];
            #pragma unroll
            for (int i = 0; i < 8; i++)
                xf[i] = *reinterpret_cast<const f32x4*>(&xs[(rg + 16 * i) * XS_STRIDE + kk]);
            #pragma unroll
            for (int j = 0; j < 4; j++)
                af[j] = *reinterpret_cast<const f32x4*>(&as[(kk + j) * NCOLS + 4 * cg]);
            #pragma unroll
            for (int i = 0; i < 8; i++) {
                acc[i] += xf[i][0] * af[0];
                acc[i] += xf[i][1] * af[1];
                acc[i] += xf[i][2] * af[2];
                acc[i] += xf[i][3] * af[3];
            }
        }
        __syncthreads();
    }

    const float s = 0.0625f;
    #pragma unroll
    for (int i = 0; i < 8; i++) {
        f32x4 v = acc[i] * s;
        *reinterpret_cast<f32x4*>(
            &ypart[((size_t)blockIdx.y * M + row0 + rg + 16 * i) * NCOLS + 4 * cg]) = v;
    }
}

// ---------------- Stage 2: out tile 64 rows x 256 cols, K = 16 ----------------
// 256 threads (4 waves). Wave w owns rows 16w..16w+15; lane c4 owns col float4.
// B column in 16 f32x4 regs; y rows read as broadcast b128 (wave-uniform addr).
__global__ __launch_bounds__(256) void lora_stage2(
    const float* __restrict__ yp,
    const float* __restrict__ Bq, const float* __restrict__ Bk,
    const float* __restrict__ Bv,
    const int* __restrict__ depth_id,
    float* __restrict__ out, int nsplit, int M)
{
    __shared__ float Bs[16 * 256];
    __shared__ float Ys[64 * 16];

    const int t    = threadIdx.x;
    const int row0 = blockIdx.x * 64;
    const int col0 = blockIdx.y * 256;
    const int z    = col0 / DIM;
    const int c0z  = col0 - z * DIM;

    const int dep = depth_id[0];
    const float* Bz = ((z == 0) ? Bq : ((z == 1) ? Bk : Bv)) + (size_t)dep * RNK * DIM;

    // stage B panel 16 x 256
    #pragma unroll
    for (int j = 0; j < 4; j++) {
        const int f = t + j * 256;
        const int k = f >> 6, c = f & 63;
        *reinterpret_cast<f32x4*>(&Bs[k * 256 + 4 * c]) =
            *reinterpret_cast<const f32x4*>(&Bz[(size_t)k * DIM + c0z + 4 * c]);
    }
    // stage y tile 64 x 16 (sum split-K partials)
    {
        const int r = t >> 2, q = t & 3;
        const size_t base = (size_t)(row0 + r) * NCOLS + z * RNK + 4 * q;
        f32x4 a = *reinterpret_cast<const f32x4*>(&yp[base]);
        for (int sp = 1; sp < nsplit; sp++)
            a += *reinterpret_cast<const f32x4*>(&yp[(size_t)sp * M * NCOLS + base]);
        *reinterpret_cast<f32x4*>(&Ys[r * 16 + 4 * q]) = a;
    }
    __syncthreads();

    const int w  = t >> 6;
    const int c4 = t & 63;

    f32x4 bk[16];
    #pragma unroll
    for (int k = 0; k < 16; k++)
        bk[k] = *reinterpret_cast<const f32x4*>(&Bs[k * 256 + 4 * c4]);

    #pragma unroll 2
    for (int i = 0; i < 16; i++) {
        const int r = 16 * w + i;
        const f32x4 y0 = *reinterpret_cast<const f32x4*>(&Ys[r * 16 + 0]);
        const f32x4 y1 = *reinterpret_cast<const f32x4*>(&Ys[r * 16 + 4]);
        const f32x4 y2 = *reinterpret_cast<const f32x4*>(&Ys[r * 16 + 8]);
        const f32x4 y3 = *reinterpret_cast<const f32x4*>(&Ys[r * 16 + 12]);
        f32x4 acc = y0[0] * bk[0];
        acc += y0[1] * bk[1];  acc += y0[2] * bk[2];  acc += y0[3] * bk[3];
        acc += y1[0] * bk[4];  acc += y1[1] * bk[5];  acc += y1[2] * bk[6];  acc += y1[3] * bk[7];
        acc += y2[0] * bk[8];  acc += y2[1] * bk[9];  acc += y2[2] * bk[10]; acc += y2[3] * bk[11];
        acc += y3[0] * bk[12]; acc += y3[1] * bk[13]; acc += y3[2] * bk[14]; acc += y3[3] * bk[15];
        __builtin_nontemporal_store(acc,
            reinterpret_cast<f32x4*>(&out[(size_t)(row0 + r) * (3 * DIM) + col0 + 4 * c4]));
    }
}

extern "C" void kernel_launch(void* const* d_in, const int* in_sizes, int n_in,
                              void* d_out, int out_size, void* d_ws, size_t ws_size,
                              hipStream_t stream) {
    const float* x  = (const float*)d_in[0];
    const float* Aq = (const float*)d_in[1];
    const float* Bq = (const float*)d_in[2];
    const float* Ak = (const float*)d_in[3];
    const float* Bk = (const float*)d_in[4];
    const float* Av = (const float*)d_in[5];
    const float* Bv = (const float*)d_in[6];
    const int* dep  = (const int*)d_in[7];
    float* out = (float*)d_out;
    float* y   = (float*)d_ws;

    const int M = in_sizes[0] / DIM;  // 25216 = 128 * 197
    const size_t y_one = (size_t)M * NCOLS * sizeof(float);
    int nsplit = 1;
    if (ws_size >= 4 * y_one) nsplit = 4;
    else if (ws_size >= 2 * y_one) nsplit = 2;
    const int kspan = DIM / nsplit;   // 192 / 384 / 768, all % 48 == 0

    lora_stage1<<<dim3(M / 128, nsplit), 192, 0, stream>>>(x, Aq, Ak, Av, dep, y, kspan, M);
    lora_stage2<<<dim3(M / 64, (3 * DIM) / 256), 256, 0, stream>>>(y, Bq, Bk, Bv, dep, out, nsplit, M);
}